// Round 4
// baseline (139.755 us; speedup 1.0000x reference)
//
#include <hip/hip_runtime.h>
#include <hip/hip_bf16.h>

typedef __attribute__((ext_vector_type(8))) short bf16x8;
typedef __attribute__((ext_vector_type(4))) float f32x4;
typedef __attribute__((ext_vector_type(2))) float f32x2;
typedef __attribute__((ext_vector_type(4))) int i32x4;
typedef __attribute__((ext_vector_type(4))) unsigned int u32x4;

#define B_   8
#define C_   64
#define T_   32
#define N_   400
#define BT_  256
#define NKT_ 13
#define L2E_ 1.4426950408889634f
#define C2_  (-13.849872392533959f)    /* -9.6 * log2(e) */
#define SH12_ (-17.312340490667560f)   /* -12 * log2(e) */

#if __has_builtin(__builtin_amdgcn_exp2f)
#define EXP2F(x) __builtin_amdgcn_exp2f(x)
#else
#define EXP2F(x) __expf((x) * 0.6931471805599453f)
#endif

// ---------------------------------------------------------------- prep: bit-pack gso
__global__ __launch_bounds__(256) void gat_prep(
    const int* __restrict__ gso, unsigned int* __restrict__ mb)
{
  int idx = blockIdx.x*256 + threadIdx.x;
  if (idx < N_*16) {
    int i = idx >> 4, kw = idx & 15;
    unsigned int bits = 0;
    if (kw < 13) {
      int j0 = kw * 32;
      #pragma unroll
      for (int bb = 0; bb < 32; ++bb) {
        int j = j0 + bb;
        if (j < N_ && gso[i*N_ + j] != 0) bits |= (1u << bb);
      }
    }
    mb[idx] = bits;
  }
}

// ---------------------------------------------------------------- fused kernel:
// one block per bt. Phase 1: stage x (bf16 pairs) + Wv, project V into LDS
// (B-fragment-readable layout) + folded scores. Phase 2: per 128-row pass,
// register softmax -> MFMA P*V (+ones row-sum) -> fused LN -> transposed store.
__global__ __launch_bounds__(1024) void gat_fused(
    const float* __restrict__ x, const float* __restrict__ Wq,
    const float* __restrict__ Wk, const float* __restrict__ Wv,
    const float* __restrict__ a_src, const float* __restrict__ a_dst,
    const float* __restrict__ gamma, const float* __restrict__ beta,
    const unsigned int* __restrict__ mb, float* __restrict__ out)
{
  __shared__ __align__(16) __hip_bfloat16 Vt[64][416];   // 53248 B
  __shared__ __align__(16) char scratch[70656];          // xs+wv  /  ob
  __shared__ __align__(16) float sd_s[2][416];           // 3328 B
  __shared__ __align__(16) float si_s[2][400];           // 3200 B
  __shared__ float wqk_s[4][64];                         // 1024 B
  __shared__ float g_s[64], b_s[64];                     // 512 B

  unsigned int (*xs)[208] = (unsigned int(*)[208])scratch;      // bf16 pairs
  float (*wv_s)[68] = (float(*)[68])(scratch + 53248);
  float (*ob)[68] = (float(*)[68])scratch;                      // phase-2 alias

  const int tid = threadIdx.x;
  const int bt = blockIdx.x;
  const int b = bt >> 5, t = bt & 31;

  // ---- phase 0: stage everything
  if (tid < 256) {           // fold a into Wq/Wk: wqk_s[type][c]
    int ww = tid >> 6, c = tid & 63, h = ww >> 1;
    const float* W = (ww & 1) ? Wk : Wq;
    const float* a = (ww & 1) ? a_dst : a_src;
    float s = 0.f;
    #pragma unroll
    for (int d = 0; d < 32; ++d) s += W[(h*32 + d)*C_ + c] * a[h*32 + d];
    wqk_s[ww][c] = s;
  } else if (tid < 320) {
    g_s[tid - 256] = gamma[tid - 256];
  } else if (tid < 384) {
    b_s[tid - 320] = beta[tid - 320];
  }
  #pragma unroll
  for (int it = 0; it < 4; ++it) {
    int idx = it*1024 + tid;
    int o = idx >> 6, c = idx & 63;
    wv_s[c][o] = Wv[o*C_ + c];
  }
  #pragma unroll
  for (int it = 0; it < 16; ++it) {          // x -> bf16 pairs in LDS
    int idx = it*1024 + tid;
    int c = idx >> 8, pr = idx & 255;
    if (pr < 208) {
      int n = pr*2;
      const float* xrow = x + ((size_t)(b*C_ + c)*T_ + t)*N_;
      float x0 = (n   < N_) ? xrow[n]   : 0.f;
      float x1 = (n+1 < N_) ? xrow[n+1] : 0.f;
      union { __hip_bfloat16 h2[2]; unsigned int u; } pk;
      pk.h2[0] = __float2bfloat16(x0);
      pk.h2[1] = __float2bfloat16(x1);
      xs[c][pr] = pk.u;
    }
  }
  __syncthreads();

  // ---- phase 1: V projection + scores (2 nodes/thread, f32x2 math)
  {
    const int pr = tid >> 2, ww = tid & 3;   // pair 0..255, type/o-group
    if (pr < 208) {
      f32x2 acc[16];
      #pragma unroll
      for (int k = 0; k < 16; ++k) acc[k] = (f32x2){0.f, 0.f};
      f32x2 sacc = {0.f, 0.f};
      #pragma unroll 4
      for (int c = 0; c < 64; ++c) {
        unsigned int xu = xs[c][pr];
        f32x2 xv;
        xv.x = __uint_as_float(xu << 16);
        xv.y = __uint_as_float(xu & 0xffff0000u);
        const f32x4* wr = (const f32x4*)&wv_s[c][ww*16];
        f32x4 w0 = wr[0], w1 = wr[1], w2 = wr[2], w3 = wr[3];
        #pragma unroll
        for (int k = 0; k < 4; ++k) acc[k]      = xv * w0[k] + acc[k];
        #pragma unroll
        for (int k = 0; k < 4; ++k) acc[4 + k]  = xv * w1[k] + acc[4 + k];
        #pragma unroll
        for (int k = 0; k < 4; ++k) acc[8 + k]  = xv * w2[k] + acc[8 + k];
        #pragma unroll
        for (int k = 0; k < 4; ++k) acc[12 + k] = xv * w3[k] + acc[12 + k];
        sacc = xv * wqk_s[ww][c] + sacc;
      }
      const int n = pr*2, hw = ww >> 1;
      if (ww & 1) {                    // dst scores (cover pad with zeros)
        sd_s[hw][n]   = sacc.x * L2E_;
        sd_s[hw][n+1] = sacc.y * L2E_;
      } else {                         // src scores
        if (n   < N_) si_s[hw][n]   = fmaf(sacc.x, L2E_, SH12_);
        if (n+1 < N_) si_s[hw][n+1] = fmaf(sacc.y, L2E_, SH12_);
      }
      #pragma unroll
      for (int k = 0; k < 16; ++k) {   // V -> LDS, packed pair write
        int o = ww*16 + k;
        union { __hip_bfloat16 h2[2]; unsigned int u; } pk;
        pk.h2[0] = __float2bfloat16(acc[k].x);
        pk.h2[1] = __float2bfloat16(acc[k].y);
        *(unsigned int*)&Vt[o][n] = pk.u;
      }
    }
  }
  __syncthreads();

  // ---- phase 2: attention + LN + store, 128 rows per pass
  const int lane = tid & 63, wave = tid >> 6;
  const int hh = wave & 1, itile = wave >> 1;      // 2 heads x 8 itiles
  const int rowA = lane & 15, quad = lane >> 4;

  bf16x8 ones;
  #pragma unroll
  for (int k = 0; k < 8; ++k) ones[k] = (short)0x3F80;

  for (int r0 = 0; r0 < N_; r0 += 128) {
    const int ibase = r0 + itile*16;
    if (ibase < N_) {
      const int irow = ibase + rowA;
      const float si1 = si_s[hh][irow];
      const u32x4* mp = (const u32x4*)(mb + irow*16);
      u32x4 mw0 = mp[0], mw1 = mp[1], mw2 = mp[2];
      unsigned int mw12 = mb[irow*16 + 12];
      const float* sdp = sd_s[hh] + quad*8;
      const __hip_bfloat16* v0p = &Vt[hh*32 + rowA][quad*8];
      const __hip_bfloat16* v1p = v0p + 16*416;

      f32x4 d0 = {0,0,0,0}, d1 = {0,0,0,0}, d2 = {0,0,0,0};
      #pragma unroll
      for (int kt = 0; kt < NKT_; ++kt) {
        unsigned int mword = (kt < 4) ? mw0[kt] : (kt < 8) ? mw1[kt-4]
                           : (kt < 12) ? mw2[kt-8] : mw12;
        unsigned int mbyte = (mword >> (quad*8)) & 0xffu;
        f32x4 s0 = *(const f32x4*)(sdp + kt*32);
        f32x4 s1 = *(const f32x4*)(sdp + kt*32 + 4);
        bf16x8 vb0 = *(const bf16x8*)(v0p + kt*32);
        bf16x8 vb1 = *(const bf16x8*)(v1p + kt*32);
        int em[8];
        #pragma unroll
        for (int jj = 0; jj < 8; ++jj) {
          float sd = (jj < 4) ? s0[jj] : s1[jj-4];
          float t1 = si1 + sd;
          float t2 = fmaf(0.2f, t1, C2_);
          float v  = fmaxf(t1, t2);
          float e  = EXP2F(v);
          int msk = ((int)(mbyte << (31 - jj))) >> 31;
          em[jj] = __float_as_int(e) & msk;
        }
        union { i32x4 i; bf16x8 v; } af;
        af.i.x = (int)__builtin_amdgcn_perm((unsigned)em[1], (unsigned)em[0], 0x07060302u);
        af.i.y = (int)__builtin_amdgcn_perm((unsigned)em[3], (unsigned)em[2], 0x07060302u);
        af.i.z = (int)__builtin_amdgcn_perm((unsigned)em[5], (unsigned)em[4], 0x07060302u);
        af.i.w = (int)__builtin_amdgcn_perm((unsigned)em[7], (unsigned)em[6], 0x07060302u);
        d0 = __builtin_amdgcn_mfma_f32_16x16x32_bf16(af.v, vb0, d0, 0, 0, 0);
        d1 = __builtin_amdgcn_mfma_f32_16x16x32_bf16(af.v, vb1, d1, 0, 0, 0);
        d2 = __builtin_amdgcn_mfma_f32_16x16x32_bf16(af.v, ones, d2, 0, 0, 0);
      }
      #pragma unroll
      for (int r = 0; r < 4; ++r) {
        float li = 1.0f / d2[r];
        int rl = itile*16 + quad*4 + r;
        ob[rl][hh*32 + rowA]      = d0[r] * li;
        ob[rl][hh*32 + 16 + rowA] = d1[r] * li;
      }
    }
    __syncthreads();

    { // fused LayerNorm over C=64 (8 lanes per row)
      int rl = tid >> 3, cgi = tid & 7;
      int n = r0 + rl;
      if (n < N_) {
        float u[8]; float s = 0.f;
        #pragma unroll
        for (int k = 0; k < 8; ++k) { u[k] = ob[rl][cgi*8 + k]; s += u[k]; }
        s += __shfl_xor(s,1); s += __shfl_xor(s,2); s += __shfl_xor(s,4);
        float mu = s * (1.f/64.f);
        float q = 0.f;
        #pragma unroll
        for (int k = 0; k < 8; ++k) { float dv = u[k]-mu; q = fmaf(dv,dv,q); }
        q += __shfl_xor(q,1); q += __shfl_xor(q,2); q += __shfl_xor(q,4);
        float rstd = rsqrtf(q*(1.f/64.f) + 1e-5f);
        #pragma unroll
        for (int k = 0; k < 8; ++k)
          ob[rl][cgi*8 + k] = (u[k]-mu)*rstd*g_s[cgi*8 + k] + b_s[cgi*8 + k];
      }
    }
    __syncthreads();

    // transposed store to (B,C,T,N): c wave-uniform, n-contiguous lanes
    #pragma unroll
    for (int it = 0; it < 8; ++it) {
      int idx = it*1024 + tid;
      int c = idx >> 7, nn = idx & 127;
      int n = r0 + nn;
      if (n < N_) out[((size_t)(b*C_ + c)*T_ + t)*N_ + n] = ob[nn][c];
    }
    __syncthreads();
  }
}

// ---------------------------------------------------------------- launch
extern "C" void kernel_launch(void* const* d_in, const int* in_sizes, int n_in,
                              void* d_out, int out_size, void* d_ws, size_t ws_size,
                              hipStream_t stream) {
  (void)in_sizes; (void)n_in; (void)out_size; (void)ws_size;
  const float* x     = (const float*)d_in[0];
  const float* Wq    = (const float*)d_in[1];
  const float* Wk    = (const float*)d_in[2];
  const float* Wv    = (const float*)d_in[3];
  const float* a_src = (const float*)d_in[4];
  const float* a_dst = (const float*)d_in[5];
  const float* gamma = (const float*)d_in[6];
  const float* beta  = (const float*)d_in[7];
  const int*   gso   = (const int*)d_in[8];
  float* out = (float*)d_out;

  unsigned int* mb = (unsigned int*)d_ws;   // 400*16 u32 = 25600 B

  gat_prep<<<26, 256, 0, stream>>>(gso, mb);
  gat_fused<<<BT_, 1024, 0, stream>>>(x, Wq, Wk, Wv, a_src, a_dst,
                                      gamma, beta, mb, out);
}

// Round 5
// 122.406 us; speedup vs baseline: 1.1417x; 1.1417x over previous
//
#include <hip/hip_runtime.h>
#include <hip/hip_bf16.h>

typedef __attribute__((ext_vector_type(8))) short bf16x8;
typedef __attribute__((ext_vector_type(4))) float f32x4;
typedef __attribute__((ext_vector_type(4))) int i32x4;
typedef __attribute__((ext_vector_type(4))) unsigned int u32x4;

#define B_   8
#define C_   64
#define T_   32
#define N_   400
#define BT_  256
#define NKT_ 13
#define CN_  12800           /* T_*N_ = c-stride in x */
#define VROW 424             /* Vt row stride (bf16): 212 words, mod32=20 -> 2-way */
#define WROW 72              /* wvb row stride (bf16): 36 words, mod32=4 -> 2-way */
#define L2E_ 1.4426950408889634f
#define C2_  (-13.849872392533959f)    /* -9.6 * log2(e) */
#define SH12_ (-17.312340490667560f)   /* -12 * log2(e) */

#if __has_builtin(__builtin_amdgcn_exp2f)
#define EXP2F(x) __builtin_amdgcn_exp2f(x)
#else
#define EXP2F(x) __expf((x) * 0.6931471805599453f)
#endif

// ---------------------------------------------------------------- prep: bit-pack gso
__global__ __launch_bounds__(256) void gat_prep(
    const int* __restrict__ gso, unsigned int* __restrict__ mb)
{
  int idx = blockIdx.x*256 + threadIdx.x;
  if (idx < N_*16) {
    int i = idx >> 4, kw = idx & 15;
    unsigned int bits = 0;
    if (kw < 13) {
      int j0 = kw * 32;
      #pragma unroll
      for (int bb = 0; bb < 32; ++bb) {
        int j = j0 + bb;
        if (j < N_ && gso[i*N_ + j] != 0) bits |= (1u << bb);
      }
    }
    mb[idx] = bits;
  }
}

// ---------------------------------------------------------------- fused kernel
// One block per bt (grid 256 = 1 block/CU).
// Phase 1: V-projection as MFMA GEMM D[o][n] = Wv_bf16 * X_bf16, with 4
//   augmented Wv rows (L2E-scaled folded wq/wk) producing scores in the same
//   MFMA. B-fragments (X) loaded straight from global; x read exactly once.
// Phase 2: per-128-row pass: register softmax -> MFMA P*V (+ones row-sum)
//   -> LDS LN -> transposed store. Vt padded to 424 (conflict-free frags).
__global__ __launch_bounds__(1024) void gat_fused(
    const float* __restrict__ x, const float* __restrict__ Wq,
    const float* __restrict__ Wk, const float* __restrict__ Wv,
    const float* __restrict__ a_src, const float* __restrict__ a_dst,
    const float* __restrict__ gamma, const float* __restrict__ beta,
    const unsigned int* __restrict__ mb, float* __restrict__ out)
{
  __shared__ __align__(16) __hip_bfloat16 Vt[64][VROW];   // 54272 B
  __shared__ __align__(16) __hip_bfloat16 wvb[80][WROW];  // 11520 B
  __shared__ __align__(16) float sd_s[2][416];            // 3328 B
  __shared__ __align__(16) float si_s[2][400];            // 3200 B
  __shared__ __align__(16) float ob[128][68];             // 34816 B
  __shared__ float g_s[64], b_s[64];                      // 512 B

  const int tid = threadIdx.x;
  const int bt = blockIdx.x;
  const int b = bt >> 5, t = bt & 31;
  const int lane = tid & 63, wave = tid >> 6;
  const int col = lane & 15, quad = lane >> 4;

  // ---- phase 0: stage weights + zero pads
  #pragma unroll
  for (int it = 0; it < 4; ++it) {            // Wv rows 0..63 -> bf16
    int idx = it*1024 + tid;
    int o = idx >> 6, c = idx & 63;
    wvb[o][c] = __float2bfloat16(Wv[o*C_ + c]);
  }
  if (tid < 256) {                            // folded score rows 64..67 (xL2E)
    int ww = tid >> 6, c = tid & 63, h = ww >> 1;
    const float* W = (ww & 1) ? Wk : Wq;
    const float* a = (ww & 1) ? a_dst : a_src;
    float s = 0.f;
    #pragma unroll
    for (int d = 0; d < 32; ++d) s += W[(h*32 + d)*C_ + c] * a[h*32 + d];
    wvb[64 + ww][c] = __float2bfloat16(s * L2E_);
  } else if (tid < 320) {
    g_s[tid - 256] = gamma[tid - 256];
  } else if (tid < 384) {
    b_s[tid - 320] = beta[tid - 320];
  } else if (tid < 416) {
    int tt = tid - 384;                       // zero sd pad cols [400,416)
    sd_s[tt >> 4][400 + (tt & 15)] = 0.f;
  }
  for (int idx = tid; idx < 12*WROW; idx += 1024)   // zero wvb rows 68..79
    wvb[68 + idx/WROW][idx % WROW] = __float2bfloat16(0.f);
  for (int idx = tid; idx < 64*24; idx += 1024)     // zero Vt cols [400,424)
    Vt[idx/24][400 + idx%24] = __float2bfloat16(0.f);
  __syncthreads();

  // ---- phase 1: projection GEMM, 25 n-tile tasks over 16 waves
  {
    const float* xbase = x + ((size_t)b*C_*T_ + t)*N_;   // elem (c,n): xbase[c*CN_+n]
    for (int nt = wave; nt < 25; nt += 16) {
      const int n0 = nt*16;
      bf16x8 bfrag[2];
      #pragma unroll
      for (int kt = 0; kt < 2; ++kt) {        // B[k=c][col=n] from global
        const float* xc = xbase + (size_t)(kt*32 + quad*8)*CN_ + n0 + col;
        union { short s[8]; bf16x8 v; } pk;
        #pragma unroll
        for (int j = 0; j < 8; ++j) {
          union { __hip_bfloat16 h; short s; } cv;
          cv.h = __float2bfloat16(xc[(size_t)j*CN_]);
          pk.s[j] = cv.s;
        }
        bfrag[kt] = pk.v;
      }
      #pragma unroll
      for (int ot = 0; ot < 5; ++ot) {
        f32x4 acc = {0.f, 0.f, 0.f, 0.f};
        #pragma unroll
        for (int kt = 0; kt < 2; ++kt) {
          bf16x8 afr = *(const bf16x8*)&wvb[ot*16 + col][kt*32 + quad*8];
          acc = __builtin_amdgcn_mfma_f32_16x16x32_bf16(afr, bfrag[kt], acc, 0, 0, 0);
        }
        // D: col(lane&15) = n - n0, row quad*4+r = o - ot*16
        if (ot < 4) {
          #pragma unroll
          for (int r = 0; r < 4; ++r)
            Vt[ot*16 + quad*4 + r][n0 + col] = __float2bfloat16(acc[r]);
        } else if (quad == 0) {               // rows 64..67 = score types
          #pragma unroll
          for (int r = 0; r < 4; ++r) {
            int h = r >> 1;
            if (r & 1) sd_s[h][n0 + col] = acc[r];
            else       si_s[h][n0 + col] = acc[r] + SH12_;
          }
        }
      }
    }
  }
  __syncthreads();

  // ---- phase 2: attention + LN + store, 128 rows per pass
  const int hh = wave & 1, itile = wave >> 1;      // 2 heads x 8 itiles
  const int rowA = col;

  bf16x8 ones;
  #pragma unroll
  for (int k = 0; k < 8; ++k) ones[k] = (short)0x3F80;

  for (int r0 = 0; r0 < N_; r0 += 128) {
    const int ibase = r0 + itile*16;
    if (ibase < N_) {
      const int irow = ibase + rowA;
      const float si1 = si_s[hh][irow];
      const u32x4* mp = (const u32x4*)(mb + irow*16);
      u32x4 mw0 = mp[0], mw1 = mp[1], mw2 = mp[2];
      unsigned int mw12 = mb[irow*16 + 12];
      const float* sdp = sd_s[hh] + quad*8;
      const __hip_bfloat16* v0p = &Vt[hh*32 + rowA][quad*8];
      const __hip_bfloat16* v1p = v0p + 16*VROW;

      f32x4 d0 = {0,0,0,0}, d1 = {0,0,0,0}, d2 = {0,0,0,0};
      #pragma unroll
      for (int kt = 0; kt < NKT_; ++kt) {
        unsigned int mword = (kt < 4) ? mw0[kt] : (kt < 8) ? mw1[kt-4]
                           : (kt < 12) ? mw2[kt-8] : mw12;
        unsigned int mbyte = (mword >> (quad*8)) & 0xffu;
        f32x4 s0 = *(const f32x4*)(sdp + kt*32);
        f32x4 s1 = *(const f32x4*)(sdp + kt*32 + 4);
        bf16x8 vb0 = *(const bf16x8*)(v0p + kt*32);
        bf16x8 vb1 = *(const bf16x8*)(v1p + kt*32);
        int em[8];
        #pragma unroll
        for (int jj = 0; jj < 8; ++jj) {
          float sd = (jj < 4) ? s0[jj] : s1[jj-4];
          float t1 = si1 + sd;
          float t2 = fmaf(0.2f, t1, C2_);
          float v  = fmaxf(t1, t2);
          float e  = EXP2F(v);
          int msk = ((int)(mbyte << (31 - jj))) >> 31;
          em[jj] = __float_as_int(e) & msk;
        }
        union { i32x4 i; bf16x8 v; } af;
        af.i.x = (int)__builtin_amdgcn_perm((unsigned)em[1], (unsigned)em[0], 0x07060302u);
        af.i.y = (int)__builtin_amdgcn_perm((unsigned)em[3], (unsigned)em[2], 0x07060302u);
        af.i.z = (int)__builtin_amdgcn_perm((unsigned)em[5], (unsigned)em[4], 0x07060302u);
        af.i.w = (int)__builtin_amdgcn_perm((unsigned)em[7], (unsigned)em[6], 0x07060302u);
        d0 = __builtin_amdgcn_mfma_f32_16x16x32_bf16(af.v, vb0, d0, 0, 0, 0);
        d1 = __builtin_amdgcn_mfma_f32_16x16x32_bf16(af.v, vb1, d1, 0, 0, 0);
        d2 = __builtin_amdgcn_mfma_f32_16x16x32_bf16(af.v, ones, d2, 0, 0, 0);
      }
      #pragma unroll
      for (int r = 0; r < 4; ++r) {
        float li = 1.0f / d2[r];
        int rl = itile*16 + quad*4 + r;
        ob[rl][hh*32 + rowA]      = d0[r] * li;
        ob[rl][hh*32 + 16 + rowA] = d1[r] * li;
      }
    }
    __syncthreads();

    { // fused LayerNorm over C=64 (8 lanes per row)
      int rl = tid >> 3, cgi = tid & 7;
      int n = r0 + rl;
      if (n < N_) {
        float u[8]; float s = 0.f;
        #pragma unroll
        for (int k = 0; k < 8; ++k) { u[k] = ob[rl][cgi*8 + k]; s += u[k]; }
        s += __shfl_xor(s,1); s += __shfl_xor(s,2); s += __shfl_xor(s,4);
        float mu = s * (1.f/64.f);
        float q = 0.f;
        #pragma unroll
        for (int k = 0; k < 8; ++k) { float dv = u[k]-mu; q = fmaf(dv,dv,q); }
        q += __shfl_xor(q,1); q += __shfl_xor(q,2); q += __shfl_xor(q,4);
        float rstd = rsqrtf(q*(1.f/64.f) + 1e-5f);
        #pragma unroll
        for (int k = 0; k < 8; ++k)
          ob[rl][cgi*8 + k] = (u[k]-mu)*rstd*g_s[cgi*8 + k] + b_s[cgi*8 + k];
      }
    }
    __syncthreads();

    // transposed store to (B,C,T,N): c wave-uniform, n-contiguous lanes
    #pragma unroll
    for (int it = 0; it < 8; ++it) {
      int idx = it*1024 + tid;
      int c = idx >> 7, nn = idx & 127;
      int n = r0 + nn;
      if (n < N_) out[((size_t)(b*C_ + c)*T_ + t)*N_ + n] = ob[nn][c];
    }
    __syncthreads();
  }
}

// ---------------------------------------------------------------- launch
extern "C" void kernel_launch(void* const* d_in, const int* in_sizes, int n_in,
                              void* d_out, int out_size, void* d_ws, size_t ws_size,
                              hipStream_t stream) {
  (void)in_sizes; (void)n_in; (void)out_size; (void)ws_size;
  const float* x     = (const float*)d_in[0];
  const float* Wq    = (const float*)d_in[1];
  const float* Wk    = (const float*)d_in[2];
  const float* Wv    = (const float*)d_in[3];
  const float* a_src = (const float*)d_in[4];
  const float* a_dst = (const float*)d_in[5];
  const float* gamma = (const float*)d_in[6];
  const float* beta  = (const float*)d_in[7];
  const int*   gso   = (const int*)d_in[8];
  float* out = (float*)d_out;

  unsigned int* mb = (unsigned int*)d_ws;   // 400*16 u32 = 25600 B

  gat_prep<<<26, 256, 0, stream>>>(gso, mb);
  gat_fused<<<BT_, 1024, 0, stream>>>(x, Wq, Wk, Wv, a_src, a_dst,
                                      gamma, beta, mb, out);
}